// Round 7
// baseline (415.660 us; speedup 1.0000x reference)
//
#include <hip/hip_runtime.h>
#include <hip/hip_bf16.h>
#include <math.h>

// VideoSwinBasicLayer: 2 swin blocks (W-MSA, SW-MSA) on (1,16,56,56,128), NH=4,
// window (8,7,7) -> L=392, nW=128, shift (4,3,3), HID=512. IO f32.
// R14: mm_kernel -> 2-phase double-buffered staging (T3-minimal): STAGE(next)
// issued before compute(cur), vmcnt(0) AFTER the MFMA cluster, raw s_barrier
// (one barrier/K-step, no compiler vmcnt-drain). LDS 32KB. Everything else = R13
// (exp2-direct attn, packed K/V tiles, MLP unsplit, LN fusions).
// ws: buf1 12.85 | bufq 38.5 (ln2o overlaps V) | hid 51.4 | wts 0.79 | bm 10.44
//   = ~114 MB of the 256 MiB workspace.

#define NTOK 50176   // 16*56*56
#define CC   128
#define LL   392
#define NWIN 128
#define NHEAD 4
#define HDIM 32
#define QKSCALE 0.17677669529663687f  // 32^-0.5
#define LOG2E   1.4426950408889634f

// attention LDS layout (u16 units)
#define KOFF    0             // K: 392 rows x 32 (granule-swizzled) = 12544 u16
#define VOFF    12544         // V^T: 32 x 392 = 12544 u16
#define POFF    25088         // P: 8 waves x 1024 (16 q-rows x 128B, swizzled)
#define LDS_U16 33280         // 66560 B -> 2 blocks/CU

#define KTILE   12544         // u16 per (w,head) K or V tile

// K tile: row-major [row][32], b128 granule g (0..3) swizzled by row bits 0..3.
// Same formula on the global-write side (mm epilogue) and LDS-read side.
#define KADDR(row, g) (((row) << 5) + ((((g) ^ ((row) & 3) ^ (((row) >> 2) & 3))) << 3))
// V^T tile: [d][392] u16, linear. stride 392 u16 = 196 dw = 4 mod 32 -> 2-way max.
#define VADDR(d, k) (VOFF + (d)*392 + (k))

#define BM_PER_HEAD (13*392*16)            // u32 per (cls,head) slice
#define BM_TOTAL    (8*4*BM_PER_HEAD)      // 10.44 MB

typedef unsigned short u16;
typedef unsigned int   u32;
typedef unsigned long long u64;
typedef __attribute__((ext_vector_type(8))) short short8;
typedef __attribute__((ext_vector_type(4))) float f32x4;
typedef __attribute__((ext_vector_type(2))) unsigned int u32x2;
typedef __attribute__((ext_vector_type(4))) unsigned int u32x4;

// async global->LDS, 16B per lane; LDS dest = wave-uniform base + lane*16.
#define GLDS(gp, lp) __builtin_amdgcn_global_load_lds( \
    (const __attribute__((address_space(1))) void*)(gp), \
    (__attribute__((address_space(3))) void*)(lp), 16, 0, 0)

__device__ __forceinline__ float b2f_lo(u32 u){ return __uint_as_float(u<<16); }
__device__ __forceinline__ float b2f_hi(u32 u){ return __uint_as_float(u & 0xffff0000u); }
__device__ __forceinline__ u16 f2b(float f){
  __hip_bfloat16 h = __float2bfloat16(f);
  return *reinterpret_cast<u16*>(&h);
}
// pack 2 f32 -> 2 bf16 (RNE) in one instruction; lo->bits[15:0], hi->bits[31:16]
__device__ __forceinline__ u32 cvtpk(float lo, float hi){
  u32 r; asm("v_cvt_pk_bf16_f32 %0, %1, %2" : "=v"(r) : "v"(lo), "v"(hi)); return r;
}

// window-ordered row r -> flat token position (roll(+shift) both directions).
__device__ __forceinline__ int row_to_pos(int r, int shifted){
  int w = r / LL, t = r - w*LL;
  int wd = w >> 6, wh = (w >> 3) & 7, ww = w & 7;
  int td = t / 49, rem = t - td*49, th = rem / 7, tw = rem - th*7;
  int d = wd*8 + td, h = wh*7 + th, x = ww*7 + tw;
  if (shifted){ d = (d+4)&15; h += 3; if (h>=56) h-=56; x += 3; if (x>=56) x-=56; }
  return (d*56 + h)*56 + x;
}

// inverse of row_to_pos with shifted=1: flat token position -> window row.
__device__ __forceinline__ int pos_to_row_sh(int p){
  int d = p / 3136, rem = p - d*3136, h = rem / 56, x = rem - h*56;
  d = (d + 12) & 15; h -= 3; if (h < 0) h += 56; x -= 3; if (x < 0) x += 56;
  int wd = d >> 3, td = d & 7;
  int wh = h / 7, th = h - wh*7, ww = x / 7, tw = x - ww*7;
  return (wd*64 + wh*8 + ww)*LL + td*49 + th*7 + tw;
}

// LayerNorm over C=128 (f32 src), bf16 out. One wave per row.
__global__ __launch_bounds__(256) void ln_kernel(
    const float* __restrict__ xf, const float* __restrict__ g,
    const float* __restrict__ b, u16* __restrict__ out, int do_map, int shifted)
{
  int wave = threadIdx.x >> 6, lane = threadIdx.x & 63;
  int r = blockIdx.x*4 + wave;
  int pos = do_map ? row_to_pos(r, shifted) : r;
  long src = (long)pos * CC;
  float v0 = xf[src+lane], v1 = xf[src+64+lane];
  float s = v0+v1, ss = v0*v0 + v1*v1;
  #pragma unroll
  for (int o=32; o>0; o>>=1){ s += __shfl_xor(s,o); ss += __shfl_xor(ss,o); }
  float mean = s*(1.f/CC);
  float var  = ss*(1.f/CC) - mean*mean;
  float rstd = rsqrtf(var + 1e-5f);
  long dst = (long)r*CC;
  out[dst + lane]      = f2b((v0-mean)*rstd*g[lane]    + b[lane]);
  out[dst + 64 + lane] = f2b((v1-mean)*rstd*g[64+lane] + b[64+lane]);
}

// All 8 weight transposes (2 blocks x {qkv,proj,fc1,fc2}) in one launch.
__global__ __launch_bounds__(256) void wtall_kernel(
    const float* __restrict__ qkvw, const float* __restrict__ projw,
    const float* __restrict__ fc1w, const float* __restrict__ fc2w,
    u16* __restrict__ wts)
{
  int t = blockIdx.x*256 + threadIdx.x;               // 0..393215
  int blk = t / 196608, r = t - blk*196608;
  const float* in; int Kd, Nd, off;
  if (r < 49152)      { in = qkvw + (size_t)blk*49152; Kd = 128; Nd = 384; off = r; }
  else if (r < 65536) { in = projw + (size_t)blk*16384; Kd = 128; Nd = 128; off = r - 49152; }
  else if (r < 131072){ in = fc1w + (size_t)blk*65536;  Kd = 128; Nd = 512; off = r - 65536; }
  else                { in = fc2w + (size_t)blk*65536;  Kd = 512; Nd = 128; off = r - 131072; }
  int n = off / Kd, k = off - n*Kd;
  wts[t] = f2b(in[k*Nd + n]);
}

// Packed bias(+mask) table in exp2 domain, layout [cls][h][s][i][jj]:
// u32 = (bf16 v(j=s*32+jj, i), bf16 v(j+16, i)).
// v = (rpb-bias - 100*maskneq(cls)) * log2e;  j>=392 -> -1e30.
__global__ __launch_bounds__(256) void biasm_kernel(
    const float* __restrict__ rpb, u32* __restrict__ bm, int total)
{
  int t = blockIdx.x*256 + threadIdx.x;
  if (t >= total) return;
  int jj = t & 15; int rest = t >> 4;
  int i  = rest % 392; rest /= 392;
  int s  = rest % 13;  rest /= 13;
  int h  = rest & 3;   int cls = rest >> 2;
  int tdi=i/49, rmi=i-tdi*49, thi=rmi/7, twi=rmi-thi*7;
  u32 pack = 0;
  #pragma unroll
  for (int half=0; half<2; half++){
    int j = s*32 + jj + half*16;
    float v = -1e30f;
    if (j < LL){
      int tdj=j/49, rmj=j-tdj*49, thj=rmj/7, twj=rmj-thj*7;
      int idx = (tdi-tdj)*169 + (thi-thj)*13 + (twi-twj) + 1267;
      v = rpb[idx*NHEAD + h];
      bool neq = ((cls&4) && ((tdi<4) != (tdj<4)))
              || ((cls&2) && ((thi<4) != (thj<4)))
              || ((cls&1) && ((twi<4) != (twj<4)));
      if (neq) v -= 100.f;
      v *= LOG2E;
    }
    pack |= ((u32)f2b(v)) << (16*half);
  }
  bm[t] = pack;
}

// MFMA GEMM, 2-phase double-buffered BK=32 staging (T3-minimal):
//   prologue STAGE(0); vmcnt(0); barrier;
//   loop { STAGE(kt+1 -> buf^1); ds_read+MFMA(buf); vmcnt(0); s_barrier; swap }
//   final compute (no prefetch).
// Raw s_barrier (not __syncthreads) so the counted/late vmcnt is not drained
// early by the compiler. One barrier per K-step; staging latency hides under
// the MFMA cluster of the previous step.
// EPI: 0 = qkv packed epilogue (y0: Q*(scale)+b -> [row][128];
//          y1: K+b -> packed swizzled tiles; y2: V+b -> V^T tiles)
//      1 = +bias, GELU -> bf16 | 2 = +bias, scatter, +Res -> f32 | 3 = accum f32
// LNF: 0 = none | 1 = (EPI2) fuse LN -> OutB at scattered pos
//      2 = (EPI3) fuse LN -> OutB at shifted-window-gathered row
template<int KD, int EPI, int LNF>
__global__ __launch_bounds__(256) void mm_kernel(
    const u16* __restrict__ A, const u16* __restrict__ Wt, int ldw,
    const float* __restrict__ bias, u16* __restrict__ OutB, int ldo,
    float* __restrict__ OutF, const float* __restrict__ Res,
    const float* __restrict__ lng, const float* __restrict__ lnb,
    float scaleq, int shifted, int use_bias)
{
  __shared__ __align__(16) u16 As[2*128*32];   // 16KB (2 buffers)
  __shared__ __align__(16) u16 Bs[2*128*32];   // 16KB
  const int tid = threadIdx.x, lane = tid & 63, wv = tid >> 6;
  const int quad = lane >> 4, l15 = lane & 15;
  const int rh = wv >> 1, ch = wv & 1;
  const int r0 = blockIdx.x * 128, n0 = blockIdx.y * 128;
  const int srow = lane >> 2, spart = (lane & 3) * 8;  // staging: 16 rows/issue
  const int nkt = KD/32;

  f32x4 acc[4][4] = {};

  auto stage = [&](int kt, int bo){
    const int k0 = kt*32;
    #pragma unroll
    for (int t=0;t<2;t++){
      const int rowbase = wv*32 + t*16;
      GLDS(&A [(long)(r0 + rowbase + srow)*KD  + k0 + spart], &As[bo + rowbase*32]);
      GLDS(&Wt[(long)(n0 + rowbase + srow)*ldw + k0 + spart], &Bs[bo + rowbase*32]);
    }
  };
  auto compute = [&](int bo){
    short8 af[4], bf[4];
    #pragma unroll
    for (int rt=0;rt<4;rt++)
      af[rt] = *reinterpret_cast<const short8*>(&As[bo + (rh*64 + rt*16 + l15)*32 + quad*8]);
    #pragma unroll
    for (int ct=0;ct<4;ct++)
      bf[ct] = *reinterpret_cast<const short8*>(&Bs[bo + (ch*64 + ct*16 + l15)*32 + quad*8]);
    #pragma unroll
    for (int rt=0;rt<4;rt++)
      #pragma unroll
      for (int ct=0;ct<4;ct++)
        acc[rt][ct] = __builtin_amdgcn_mfma_f32_16x16x32_bf16(af[rt], bf[ct], acc[rt][ct], 0,0,0);
  };

  // prologue
  stage(0, 0);
  asm volatile("s_waitcnt vmcnt(0)" ::: "memory");
  __builtin_amdgcn_s_barrier();

  int cur = 0;
  for (int kt = 0; kt < nkt-1; kt++){
    stage(kt+1, 4096 - cur);          // issue next-step loads (other buffer)
    compute(cur);                      // MFMA on current (hides load latency)
    asm volatile("s_waitcnt vmcnt(0)" ::: "memory");
    __builtin_amdgcn_s_barrier();      // next buffer ready; cur free to restage
    cur = 4096 - cur;
  }
  compute(cur);                        // final K-step, no prefetch

  if (EPI == 0){
    const int y = blockIdx.y;
    if (y == 0){
      #pragma unroll
      for (int rt=0;rt<4;rt++)
        #pragma unroll
        for (int rr=0;rr<4;rr++){
          const int row_g = r0 + rh*64 + rt*16 + quad*4 + rr;
          #pragma unroll
          for (int ct=0;ct<4;ct++){
            const int c = ch*64 + ct*16 + l15;
            float v = (acc[rt][ct][rr] + bias[c]) * scaleq;
            OutB[(long)row_g*128 + c] = f2b(v);
          }
        }
    } else if (y == 1){
      u16* Kreg = OutB + (size_t)NTOK*128;
      #pragma unroll
      for (int rt=0;rt<4;rt++)
        #pragma unroll
        for (int rr=0;rr<4;rr++){
          const int row_g = r0 + rh*64 + rt*16 + quad*4 + rr;
          const int wi = row_g / 392, key = row_g - wi*392;
          #pragma unroll
          for (int ct=0;ct<4;ct++){
            const int c = ch*64 + ct*16 + l15;
            const int hd = c >> 5, d = c & 31;
            float v = acc[rt][ct][rr] + bias[128 + c];
            Kreg[(size_t)(wi*4 + hd)*KTILE + KADDR(key, d>>3) + (d&7)] = f2b(v);
          }
        }
    } else {
      u16* Vreg = OutB + (size_t)NTOK*256;
      #pragma unroll
      for (int rt=0;rt<4;rt++){
        const int rbase = r0 + rh*64 + rt*16 + quad*4;    // 4-aligned; 392%4==0
        const int wi = rbase / 392, key0 = rbase - wi*392; // -> never crosses w
        #pragma unroll
        for (int ct=0;ct<4;ct++){
          const int c = ch*64 + ct*16 + l15;
          const int hd = c >> 5, d = c & 31;
          const float bb = bias[256 + c];
          u32 lo = cvtpk(acc[rt][ct][0] + bb, acc[rt][ct][1] + bb);
          u32 hi = cvtpk(acc[rt][ct][2] + bb, acc[rt][ct][3] + bb);
          u64 pk = (u64)lo | ((u64)hi << 32);
          *reinterpret_cast<u64*>(&Vreg[(size_t)(wi*4 + hd)*KTILE + (size_t)d*392 + key0]) = pk;
        }
      }
    }
  } else if (LNF == 0){
    #pragma unroll
    for (int rt=0;rt<4;rt++){
      #pragma unroll
      for (int rr=0;rr<4;rr++){
        const int row_g = r0 + rh*64 + rt*16 + quad*4 + rr;
        long pos = 0;
        if (EPI == 2) pos = (long)row_to_pos(row_g, shifted) * CC;
        #pragma unroll
        for (int ct=0;ct<4;ct++){
          const int col_g = n0 + ch*64 + ct*16 + l15;
          float v = acc[rt][ct][rr];
          if (EPI == 1){
            v += bias[col_g];
            v = 0.5f*v*(1.f + erff(v*0.70710678118654752f));
            OutB[(long)row_g*ldo + col_g] = f2b(v);
          } else if (EPI == 2){
            OutF[pos + col_g] = Res[pos + col_g] + v + bias[col_g];
          } else {
            float o = OutF[(long)row_g*CC + col_g] + v;
            if (use_bias) o += bias[col_g];
            OutF[(long)row_g*CC + col_g] = o;
          }
        }
      }
    }
  } else {
    // fused LayerNorm epilogue (requires full 128-col rows: gridDim.y == 1).
    // red scratch lives in As buffer 0; final compute used buffer 1 (nkt even)
    // -> disjoint, no barrier needed before the scratch writes.
    float* red = (float*)As;     // [128 rows][2 ch][2 stats] = 2KB
    int pose[4][4];
    #pragma unroll
    for (int rt=0;rt<4;rt++){
      #pragma unroll
      for (int rr=0;rr<4;rr++){
        const int row_g = r0 + rh*64 + rt*16 + quad*4 + rr;
        int pos = (EPI == 2) ? row_to_pos(row_g, shifted) : row_g;
        pose[rt][rr] = pos;
        long pb = (long)pos * CC;
        float s = 0.f, ss = 0.f;
        #pragma unroll
        for (int ct=0;ct<4;ct++){
          const int col_g = n0 + ch*64 + ct*16 + l15;
          float v = acc[rt][ct][rr];
          float o;
          if (EPI == 2) o = Res[pb + col_g] + v + bias[col_g];
          else { o = OutF[pb + col_g] + v; if (use_bias) o += bias[col_g]; }
          OutF[pb + col_g] = o;
          acc[rt][ct][rr] = o;
          s += o; ss += o*o;
        }
        #pragma unroll
        for (int off=1; off<16; off<<=1){
          s  += __shfl_xor(s,  off);
          ss += __shfl_xor(ss, off);
        }
        if (l15 == 0){
          int rl = rh*64 + rt*16 + quad*4 + rr;
          red[rl*4 + ch*2]     = s;
          red[rl*4 + ch*2 + 1] = ss;
        }
      }
    }
    __syncthreads();
    #pragma unroll
    for (int rt=0;rt<4;rt++){
      #pragma unroll
      for (int rr=0;rr<4;rr++){
        const int rl = rh*64 + rt*16 + quad*4 + rr;
        float st  = red[rl*4]     + red[rl*4 + 2];
        float sst = red[rl*4 + 1] + red[rl*4 + 3];
        float mean = st*(1.f/128.f);
        float var  = sst*(1.f/128.f) - mean*mean;
        float rstd = rsqrtf(var + 1e-5f);
        long oidx;
        if (LNF == 1) oidx = (long)pose[rt][rr] * CC;            // linear-pos out
        else          oidx = (long)pos_to_row_sh(pose[rt][rr]) * CC; // window out
        #pragma unroll
        for (int ct=0;ct<4;ct++){
          const int col_g = n0 + ch*64 + ct*16 + l15;
          float val = (acc[rt][ct][rr] - mean)*rstd*lng[col_g] + lnb[col_g];
          OutB[oidx + col_g] = f2b(val);
        }
      }
    }
  }
}

// MFMA flash attention, S^T orientation. One block per (window, head); 8 waves
// x 16-row q-tiles (qt += 8). K/V^T staged via linear global_load_lds from the
// packed tiles the qkv GEMM emitted. exp2-DIRECT softmax: no max tracking
// (logits structurally bounded; mask bias -144 -> exp2 -> exact 0). Per-lane
// partial denominator, reduced once per q-tile.
__global__ __launch_bounds__(512, 4) void attn_kernel(
    const u16* __restrict__ qkv, const u32* __restrict__ bm,
    u16* __restrict__ out, int shifted)
{
  __shared__ __align__(16) u16 lds[LDS_U16];

  const int w = blockIdx.x >> 2, head = blockIdx.x & 3;
  const int tid = threadIdx.x, lane = tid & 63, wave = tid >> 6;
  const int quad = lane >> 4, l15 = lane & 15;
  const int wd = w>>6, wh = (w>>3)&7, ww = w&7;
  const int cls = shifted ? (((wd!=0)?4:0) | ((wh==7)?2:0) | ((ww==7)?1:0)) : 0;
  const u32* __restrict__ bmh = bm + (size_t)(cls*NHEAD + head)*BM_PER_HEAD;
  const int pbase = POFF + wave*1024;
  const int swz = l15 & 7;
  const int prow = pbase + l15*64;
  const int q2 = quad >> 1, qh = (quad & 1) << 2;

  // stage K tile (25088B) and V^T tile (25088B), both linear
  {
    const u16* Kg = qkv + (size_t)NTOK*128 + (size_t)(w*4+head)*KTILE;
    const u16* Vg = qkv + (size_t)NTOK*256 + (size_t)(w*4+head)*KTILE;
    #pragma unroll
    for (int n = 0; n < 3; n++){
      GLDS(Kg + n*4096 + wave*512 + (lane<<3), &lds[KOFF + n*4096 + wave*512]);
      GLDS(Vg + n*4096 + wave*512 + (lane<<3), &lds[VOFF + n*4096 + wave*512]);
    }
    if (tid < 32){
      GLDS(Kg + 12288 + (lane<<3), &lds[KOFF + 12288]);
      GLDS(Vg + 12288 + (lane<<3), &lds[VOFF + 12288]);
    }
  }
  __syncthreads();

  for (int qt = wave; qt < 25; qt += 8){
    int iq = qt*16 + l15; if (iq > LL-1) iq = LL-1;
    short8 qf = *reinterpret_cast<const short8*>(
        &qkv[((size_t)(w*LL + iq))*128 + head*HDIM + quad*8]);

    float ls = 0.f;
    f32x4 oc0 = {0.f,0.f,0.f,0.f}, oc1 = {0.f,0.f,0.f,0.f};

    const int bmrow = iq*16 + quad*4;
    u32x4 bmA = *reinterpret_cast<const u32x4*>(&bmh[bmrow]);            // s=0
    u32x4 bmB = *reinterpret_cast<const u32x4*>(&bmh[392*16 + bmrow]);   // s=1
    short8 kf0 = *reinterpret_cast<const short8*>(&lds[KOFF + KADDR(     l15, quad)]);
    short8 kf1 = *reinterpret_cast<const short8*>(&lds[KOFF + KADDR(16 + l15, quad)]);
    short8 kf2 = *reinterpret_cast<const short8*>(&lds[KOFF + KADDR(32 + l15, quad)]);
    short8 kf3 = *reinterpret_cast<const short8*>(&lds[KOFF + KADDR(48 + l15, quad)]);

    for (int it = 0; it < 6; it++){
      const int kb = it*64;
      // prefetch next 64-key group (or the clamped 32-key tail when it==5)
      u32x4 bmAn = {}, bmBn = {};
      short8 kn0 = {}, kn1 = {}, kn2 = {}, kn3 = {};
      if (it < 5){
        bmAn = *reinterpret_cast<const u32x4*>(&bmh[(2*it+2)*392*16 + bmrow]);
        bmBn = *reinterpret_cast<const u32x4*>(&bmh[(2*it+3)*392*16 + bmrow]);
        kn0 = *reinterpret_cast<const short8*>(&lds[KOFF + KADDR(kb + 64 + l15, quad)]);
        kn1 = *reinterpret_cast<const short8*>(&lds[KOFF + KADDR(kb + 80 + l15, quad)]);
        kn2 = *reinterpret_cast<const short8*>(&lds[KOFF + KADDR(kb + 96 + l15, quad)]);
        kn3 = *reinterpret_cast<const short8*>(&lds[KOFF + KADDR(kb +112 + l15, quad)]);
      } else {
        bmAn = *reinterpret_cast<const u32x4*>(&bmh[12*392*16 + bmrow]);
        // tail K rows clamped to real rows 384..391; bias -1e30 kills keys>=392
        kn0 = *reinterpret_cast<const short8*>(&lds[KOFF + KADDR(384 + (l15 & 7), quad)]);
        kn1 = kn0;
      }

      f32x4 z = {0.f,0.f,0.f,0.f};
      __builtin_amdgcn_s_setprio(1);
      f32x4 c0 = __builtin_amdgcn_mfma_f32_16x16x32_bf16(kf0, qf, z, 0,0,0);
      f32x4 c1 = __builtin_amdgcn_mfma_f32_16x16x32_bf16(kf1, qf, z, 0,0,0);
      f32x4 c2 = __builtin_amdgcn_mfma_f32_16x16x32_bf16(kf2, qf, z, 0,0,0);
      f32x4 c3 = __builtin_amdgcn_mfma_f32_16x16x32_bf16(kf3, qf, z, 0,0,0);
      __builtin_amdgcn_s_setprio(0);
      // c0[r]: S[key=kb+quad*4+r][q=iq]; c1: +16; c2: +32; c3: +48 (log2 dom.)

      float p0[4], p1[4], p2[4], p3[4];
      #pragma unroll
      for (int r=0;r<4;r++){
        p0[r] = exp2f(c0[r] + b2f_lo(bmA[r]));
        p1[r] = exp2f(c1[r] + b2f_hi(bmA[r]));
        p2[r] = exp2f(c2[r] + b2f_lo(bmB[r]));
        p3[r] = exp2f(c3[r] + b2f_hi(bmB[r]));
        ls += (p0[r] + p1[r]) + (p2[r] + p3[r]);
      }

      // P -> wave-private LDS (16 rows x 8 granules, granule ^= l15&7)
      u32x2 w0, w1, w2, w3;
      w0.x = cvtpk(p0[0], p0[1]); w0.y = cvtpk(p0[2], p0[3]);
      w1.x = cvtpk(p1[0], p1[1]); w1.y = cvtpk(p1[2], p1[3]);
      w2.x = cvtpk(p2[0], p2[1]); w2.y = cvtpk(p2[2], p2[3]);
      w3.x = cvtpk(p3[0], p3[1]); w3.y = cvtpk(p3[2], p3[3]);
      *reinterpret_cast<u32x2*>(&lds[prow + (((0 + q2) ^ swz) << 3) + qh]) = w0;
      *reinterpret_cast<u32x2*>(&lds[prow + (((2 + q2) ^ swz) << 3) + qh]) = w1;
      *reinterpret_cast<u32x2*>(&lds[prow + (((4 + q2) ^ swz) << 3) + qh]) = w2;
      *reinterpret_cast<u32x2*>(&lds[prow + (((6 + q2) ^ swz) << 3) + qh]) = w3;

      short8 pa0 = *reinterpret_cast<const short8*>(&lds[prow + (((quad    ) ^ swz) << 3)]);
      short8 pa1 = *reinterpret_cast<const short8*>(&lds[prow + (((quad + 4) ^ swz) << 3)]);
      short8 vb00 = *reinterpret_cast<const short8*>(&lds[VADDR(     l15, kb      + quad*8)]);
      short8 vb01 = *reinterpret_cast<const short8*>(&lds[VADDR(16 + l15, kb      + quad*8)]);
      short8 vb10 = *reinterpret_cast<const short8*>(&lds[VADDR(     l15, kb + 32 + quad*8)]);
      short8 vb11 = *reinterpret_cast<const short8*>(&lds[VADDR(16 + l15, kb + 32 + quad*8)]);
      __builtin_amdgcn_s_setprio(1);
      oc0 = __builtin_amdgcn_mfma_f32_16x16x32_bf16(pa0, vb00, oc0, 0,0,0);
      oc1 = __builtin_amdgcn_mfma_f32_16x16x32_bf16(pa0, vb01, oc1, 0,0,0);
      oc0 = __builtin_amdgcn_mfma_f32_16x16x32_bf16(pa1, vb10, oc0, 0,0,0);
      oc1 = __builtin_amdgcn_mfma_f32_16x16x32_bf16(pa1, vb11, oc1, 0,0,0);
      __builtin_amdgcn_s_setprio(0);

      bmA = bmAn; bmB = bmBn;
      kf0 = kn0; kf1 = kn1; kf2 = kn2; kf3 = kn3;
    }

    // tail: keys 384..415 (K rows clamped; bias kills keys >= 392)
    {
      f32x4 z = {0.f,0.f,0.f,0.f};
      f32x4 c0 = __builtin_amdgcn_mfma_f32_16x16x32_bf16(kf0, qf, z, 0,0,0);
      f32x4 c1 = __builtin_amdgcn_mfma_f32_16x16x32_bf16(kf1, qf, z, 0,0,0);
      float p0[4], p1[4];
      #pragma unroll
      for (int r=0;r<4;r++){
        p0[r] = exp2f(c0[r] + b2f_lo(bmA[r]));
        p1[r] = exp2f(c1[r] + b2f_hi(bmA[r]));
        ls += p0[r] + p1[r];
      }
      u32x2 w0, w1;
      w0.x = cvtpk(p0[0], p0[1]); w0.y = cvtpk(p0[2], p0[3]);
      w1.x = cvtpk(p1[0], p1[1]); w1.y = cvtpk(p1[2], p1[3]);
      *reinterpret_cast<u32x2*>(&lds[prow + (((0 + q2) ^ swz) << 3) + qh]) = w0;
      *reinterpret_cast<u32x2*>(&lds[prow + (((2 + q2) ^ swz) << 3) + qh]) = w1;
      short8 pa0 = *reinterpret_cast<const short8*>(&lds[prow + ((quad ^ swz) << 3)]);
      // V clamped to keys 384..391 for all k-slots; P==0 for keys >= 392
      short8 vb0 = *reinterpret_cast<const short8*>(&lds[VADDR(     l15, 384)]);
      short8 vb1 = *reinterpret_cast<const short8*>(&lds[VADDR(16 + l15, 384)]);
      oc0 = __builtin_amdgcn_mfma_f32_16x16x32_bf16(pa0, vb0, oc0, 0,0,0);
      oc1 = __builtin_amdgcn_mfma_f32_16x16x32_bf16(pa0, vb1, oc1, 0,0,0);
    }

    // denominator: reduce per-lane partials once per q-tile
    ls += __shfl_xor(ls, 16);
    ls += __shfl_xor(ls, 32);
    float inv = 1.f / ls;
    #pragma unroll
    for (int r=0;r<4;r++){
      float invr = __shfl(inv, quad*4 + r);
      int i = qt*16 + quad*4 + r;
      if (i < LL){
        long o = ((long)(w*LL + i))*CC + head*HDIM;
        out[o + l15]      = f2b(oc0[r]*invr);
        out[o + 16 + l15] = f2b(oc1[r]*invr);
      }
    }
  }
}

extern "C" void kernel_launch(void* const* d_in, const int* in_sizes, int n_in,
                              void* d_out, int out_size, void* d_ws, size_t ws_size,
                              hipStream_t stream)
{
  const float* x     = (const float*)d_in[0];
  const float* ln1g  = (const float*)d_in[1];
  const float* ln1b  = (const float*)d_in[2];
  const float* qkvw  = (const float*)d_in[3];
  const float* qkvb  = (const float*)d_in[4];
  const float* rpb   = (const float*)d_in[5];
  const float* projw = (const float*)d_in[6];
  const float* projb = (const float*)d_in[7];
  const float* ln2g  = (const float*)d_in[8];
  const float* ln2b  = (const float*)d_in[9];
  const float* fc1w  = (const float*)d_in[10];
  const float* fc1b  = (const float*)d_in[11];
  const float* fc2w  = (const float*)d_in[12];
  const float* fc2b  = (const float*)d_in[13];
  float* outf = (float*)d_out;                  // f32 residual stream / output

  u16* buf1 = (u16*)d_ws;                       // bf16 act (window space), NTOK*128
  u16* bufq = buf1 + (size_t)NTOK*CC;           // Q | Kpack | V^T  (NTOK*384 u16)
  u16* ln2o = bufq + (size_t)NTOK*256;          // LN2 out (overlays V^T, dead then)
  u16* hid  = bufq + (size_t)NTOK*384;          // MLP hidden, NTOK*512 u16
  u16* wts  = hid  + (size_t)NTOK*512;          // transposed bf16 weights
  u32* bm   = (u32*)(wts + 393216);             // packed bias+mask table

  // all weight transposes in one launch
  wtall_kernel<<<1536, 256, 0, stream>>>(qkvw, projw, fc1w, fc2w, wts);

  for (int blk = 0; blk < 2; ++blk){
    const int sh = blk;
    const float* resid = (blk==0) ? x : outf;
    u16* wb = wts + (size_t)blk*196608;

    // block 0 (unshifted) only uses mask class 0 -> build 1/8 of the table
    const int bmtot = (blk==0) ? 4*BM_PER_HEAD : BM_TOTAL;
    biasm_kernel<<<(bmtot+255)/256, 256, 0, stream>>>(
        rpb + (size_t)blk*2535*NHEAD, bm, bmtot);
    // LN1 + roll + window gather: separate kernel only for block 0 (from x);
    // block 1's LN1 is fused into block 0's fc2 epilogue.
    if (blk == 0)
      ln_kernel<<<NTOK/4, 256, 0, stream>>>(resid,
          ln1g, ln1b, buf1, 1, 0);
    // QKV GEMM -> packed attention tiles (q pre-scaled by 32^-0.5 * log2e)
    mm_kernel<128,0,0><<<dim3(392,3), 256, 0, stream>>>(
        buf1, wb, 128, qkvb + blk*384, bufq, 128,
        nullptr, nullptr, nullptr, nullptr, QKSCALE*LOG2E, 0, 0);
    // attention (128 windows x 4 heads), 8 waves/block
    attn_kernel<<<NWIN*NHEAD, 512, 0, stream>>>(bufq, bm, buf1, sh);
    // proj + reverse/roll-back scatter + residual -> outf; fused LN2 -> ln2o
    mm_kernel<128,2,1><<<dim3(392,1), 256, 0, stream>>>(
        buf1, wb+49152, 128, projb + blk*CC, ln2o, 0,
        outf, resid, ln2g + blk*CC, ln2b + blk*CC, 1.f, sh, 0);
    // MLP: fc1 one launch (4 column-blocks) -> hid[NTOK][512]
    mm_kernel<128,1,0><<<dim3(392,4), 256, 0, stream>>>(
        ln2o, wb + 65536, 128,
        fc1b + blk*512, hid, 512,
        nullptr, nullptr, nullptr, nullptr, 1.f, 0, 0);
    // fc2 one launch, KD=512, +bias, +residual(outf in place)
    if (blk == 0){
      // fuse LN1(+shifted window gather) for block 1 -> buf1
      mm_kernel<512,3,2><<<dim3(392,1), 256, 0, stream>>>(
          hid, wb + 131072, 512,
          fc2b, buf1, 0,
          outf, nullptr, ln1g + CC, ln1b + CC, 1.f, 0, 1);
    } else {
      mm_kernel<512,3,0><<<dim3(392,1), 256, 0, stream>>>(
          hid, wb + 131072, 512,
          fc2b + CC, nullptr, 0,
          outf, nullptr, nullptr, nullptr, 1.f, 0, 1);
    }
  }
}

// Round 8
// 374.320 us; speedup vs baseline: 1.1104x; 1.1104x over previous
//
#include <hip/hip_runtime.h>
#include <hip/hip_bf16.h>
#include <math.h>

// VideoSwinBasicLayer: 2 swin blocks (W-MSA, SW-MSA) on (1,16,56,56,128), NH=4,
// window (8,7,7) -> L=392, nW=128, shift (4,3,3), HID=512. IO f32.
// R15: mm_kernel -> 8-wave (512-thread) blocks, 2x4 wave grid, per-wave 64x32
// output (acc 4x2). 1 A + 1 B global_load_lds per wave per K-step. Doubles
// resident waves/CU (TLP latency hiding; R14 proved ILP dbuf alone is null).
// Everything else = R14 (exp2-direct attn, packed K/V tiles, MLP unsplit,
// LN fusions, 2-phase dbuf skeleton).
// ws: buf1 12.85 | bufq 38.5 (ln2o overlaps V) | hid 51.4 | wts 0.79 | bm 10.44

#define NTOK 50176   // 16*56*56
#define CC   128
#define LL   392
#define NWIN 128
#define NHEAD 4
#define HDIM 32
#define QKSCALE 0.17677669529663687f  // 32^-0.5
#define LOG2E   1.4426950408889634f

// attention LDS layout (u16 units)
#define KOFF    0             // K: 392 rows x 32 (granule-swizzled) = 12544 u16
#define VOFF    12544         // V^T: 32 x 392 = 12544 u16
#define POFF    25088         // P: 8 waves x 1024 (16 q-rows x 128B, swizzled)
#define LDS_U16 33280         // 66560 B -> 2 blocks/CU

#define KTILE   12544         // u16 per (w,head) K or V tile

// K tile: row-major [row][32], b128 granule g (0..3) swizzled by row bits 0..3.
// Same formula on the global-write side (mm epilogue) and LDS-read side.
#define KADDR(row, g) (((row) << 5) + ((((g) ^ ((row) & 3) ^ (((row) >> 2) & 3))) << 3))
// V^T tile: [d][392] u16, linear. stride 392 u16 = 196 dw = 4 mod 32 -> 2-way max.
#define VADDR(d, k) (VOFF + (d)*392 + (k))

#define BM_PER_HEAD (13*392*16)            // u32 per (cls,head) slice
#define BM_TOTAL    (8*4*BM_PER_HEAD)      // 10.44 MB

typedef unsigned short u16;
typedef unsigned int   u32;
typedef unsigned long long u64;
typedef __attribute__((ext_vector_type(8))) short short8;
typedef __attribute__((ext_vector_type(4))) float f32x4;
typedef __attribute__((ext_vector_type(2))) unsigned int u32x2;
typedef __attribute__((ext_vector_type(4))) unsigned int u32x4;

// async global->LDS, 16B per lane; LDS dest = wave-uniform base + lane*16.
#define GLDS(gp, lp) __builtin_amdgcn_global_load_lds( \
    (const __attribute__((address_space(1))) void*)(gp), \
    (__attribute__((address_space(3))) void*)(lp), 16, 0, 0)

__device__ __forceinline__ float b2f_lo(u32 u){ return __uint_as_float(u<<16); }
__device__ __forceinline__ float b2f_hi(u32 u){ return __uint_as_float(u & 0xffff0000u); }
__device__ __forceinline__ u16 f2b(float f){
  __hip_bfloat16 h = __float2bfloat16(f);
  return *reinterpret_cast<u16*>(&h);
}
// pack 2 f32 -> 2 bf16 (RNE) in one instruction; lo->bits[15:0], hi->bits[31:16]
__device__ __forceinline__ u32 cvtpk(float lo, float hi){
  u32 r; asm("v_cvt_pk_bf16_f32 %0, %1, %2" : "=v"(r) : "v"(lo), "v"(hi)); return r;
}

// window-ordered row r -> flat token position (roll(+shift) both directions).
__device__ __forceinline__ int row_to_pos(int r, int shifted){
  int w = r / LL, t = r - w*LL;
  int wd = w >> 6, wh = (w >> 3) & 7, ww = w & 7;
  int td = t / 49, rem = t - td*49, th = rem / 7, tw = rem - th*7;
  int d = wd*8 + td, h = wh*7 + th, x = ww*7 + tw;
  if (shifted){ d = (d+4)&15; h += 3; if (h>=56) h-=56; x += 3; if (x>=56) x-=56; }
  return (d*56 + h)*56 + x;
}

// inverse of row_to_pos with shifted=1: flat token position -> window row.
__device__ __forceinline__ int pos_to_row_sh(int p){
  int d = p / 3136, rem = p - d*3136, h = rem / 56, x = rem - h*56;
  d = (d + 12) & 15; h -= 3; if (h < 0) h += 56; x -= 3; if (x < 0) x += 56;
  int wd = d >> 3, td = d & 7;
  int wh = h / 7, th = h - wh*7, ww = x / 7, tw = x - ww*7;
  return (wd*64 + wh*8 + ww)*LL + td*49 + th*7 + tw;
}

// LayerNorm over C=128 (f32 src), bf16 out. One wave per row.
__global__ __launch_bounds__(256) void ln_kernel(
    const float* __restrict__ xf, const float* __restrict__ g,
    const float* __restrict__ b, u16* __restrict__ out, int do_map, int shifted)
{
  int wave = threadIdx.x >> 6, lane = threadIdx.x & 63;
  int r = blockIdx.x*4 + wave;
  int pos = do_map ? row_to_pos(r, shifted) : r;
  long src = (long)pos * CC;
  float v0 = xf[src+lane], v1 = xf[src+64+lane];
  float s = v0+v1, ss = v0*v0 + v1*v1;
  #pragma unroll
  for (int o=32; o>0; o>>=1){ s += __shfl_xor(s,o); ss += __shfl_xor(ss,o); }
  float mean = s*(1.f/CC);
  float var  = ss*(1.f/CC) - mean*mean;
  float rstd = rsqrtf(var + 1e-5f);
  long dst = (long)r*CC;
  out[dst + lane]      = f2b((v0-mean)*rstd*g[lane]    + b[lane]);
  out[dst + 64 + lane] = f2b((v1-mean)*rstd*g[64+lane] + b[64+lane]);
}

// All 8 weight transposes (2 blocks x {qkv,proj,fc1,fc2}) in one launch.
__global__ __launch_bounds__(256) void wtall_kernel(
    const float* __restrict__ qkvw, const float* __restrict__ projw,
    const float* __restrict__ fc1w, const float* __restrict__ fc2w,
    u16* __restrict__ wts)
{
  int t = blockIdx.x*256 + threadIdx.x;               // 0..393215
  int blk = t / 196608, r = t - blk*196608;
  const float* in; int Kd, Nd, off;
  if (r < 49152)      { in = qkvw + (size_t)blk*49152; Kd = 128; Nd = 384; off = r; }
  else if (r < 65536) { in = projw + (size_t)blk*16384; Kd = 128; Nd = 128; off = r - 49152; }
  else if (r < 131072){ in = fc1w + (size_t)blk*65536;  Kd = 128; Nd = 512; off = r - 65536; }
  else                { in = fc2w + (size_t)blk*65536;  Kd = 512; Nd = 128; off = r - 131072; }
  int n = off / Kd, k = off - n*Kd;
  wts[t] = f2b(in[k*Nd + n]);
}

// Packed bias(+mask) table in exp2 domain, layout [cls][h][s][i][jj]:
// u32 = (bf16 v(j=s*32+jj, i), bf16 v(j+16, i)).
// v = (rpb-bias - 100*maskneq(cls)) * log2e;  j>=392 -> -1e30.
__global__ __launch_bounds__(256) void biasm_kernel(
    const float* __restrict__ rpb, u32* __restrict__ bm, int total)
{
  int t = blockIdx.x*256 + threadIdx.x;
  if (t >= total) return;
  int jj = t & 15; int rest = t >> 4;
  int i  = rest % 392; rest /= 392;
  int s  = rest % 13;  rest /= 13;
  int h  = rest & 3;   int cls = rest >> 2;
  int tdi=i/49, rmi=i-tdi*49, thi=rmi/7, twi=rmi-thi*7;
  u32 pack = 0;
  #pragma unroll
  for (int half=0; half<2; half++){
    int j = s*32 + jj + half*16;
    float v = -1e30f;
    if (j < LL){
      int tdj=j/49, rmj=j-tdj*49, thj=rmj/7, twj=rmj-thj*7;
      int idx = (tdi-tdj)*169 + (thi-thj)*13 + (twi-twj) + 1267;
      v = rpb[idx*NHEAD + h];
      bool neq = ((cls&4) && ((tdi<4) != (tdj<4)))
              || ((cls&2) && ((thi<4) != (thj<4)))
              || ((cls&1) && ((twi<4) != (twj<4)));
      if (neq) v -= 100.f;
      v *= LOG2E;
    }
    pack |= ((u32)f2b(v)) << (16*half);
  }
  bm[t] = pack;
}

// MFMA GEMM, 8-wave (512-thread) blocks, 2x4 wave grid, per-wave 64x32 output.
// 2-phase double-buffered BK=32 staging; 1 A + 1 B global_load_lds per wave per
// K-step; vmcnt(0) after the MFMA cluster; raw s_barrier.
// EPI: 0 = qkv packed epilogue (y0: Q*(scale)+b -> [row][128];
//          y1: K+b -> packed swizzled tiles; y2: V+b -> V^T tiles)
//      1 = +bias, GELU -> bf16 | 2 = +bias, scatter, +Res -> f32 | 3 = accum f32
// LNF: 0 = none | 1 = (EPI2) fuse LN -> OutB at scattered pos
//      2 = (EPI3) fuse LN -> OutB at shifted-window-gathered row
template<int KD, int EPI, int LNF>
__global__ __launch_bounds__(512) void mm_kernel(
    const u16* __restrict__ A, const u16* __restrict__ Wt, int ldw,
    const float* __restrict__ bias, u16* __restrict__ OutB, int ldo,
    float* __restrict__ OutF, const float* __restrict__ Res,
    const float* __restrict__ lng, const float* __restrict__ lnb,
    float scaleq, int shifted, int use_bias)
{
  __shared__ __align__(16) u16 As[2*128*32];   // 16KB (2 buffers)
  __shared__ __align__(16) u16 Bs[2*128*32];   // 16KB
  const int tid = threadIdx.x, lane = tid & 63, wv = tid >> 6;  // 0..7
  const int quad = lane >> 4, l15 = lane & 15;
  const int rh = wv >> 2, ch = wv & 3;          // 2 x 4 wave grid
  const int r0 = blockIdx.x * 128, n0 = blockIdx.y * 128;
  const int srow = lane >> 2, spart = (lane & 3) * 8;  // staging: 16 rows/issue
  const int nkt = KD/32;

  f32x4 acc[4][2] = {};

  auto stage = [&](int kt, int bo){
    const int k0 = kt*32;
    GLDS(&A [(long)(r0 + wv*16 + srow)*KD  + k0 + spart], &As[bo + wv*512]);
    GLDS(&Wt[(long)(n0 + wv*16 + srow)*ldw + k0 + spart], &Bs[bo + wv*512]);
  };
  auto compute = [&](int bo){
    short8 af[4], bf[2];
    #pragma unroll
    for (int rt=0;rt<4;rt++)
      af[rt] = *reinterpret_cast<const short8*>(&As[bo + (rh*64 + rt*16 + l15)*32 + quad*8]);
    #pragma unroll
    for (int ct=0;ct<2;ct++)
      bf[ct] = *reinterpret_cast<const short8*>(&Bs[bo + (ch*32 + ct*16 + l15)*32 + quad*8]);
    #pragma unroll
    for (int rt=0;rt<4;rt++)
      #pragma unroll
      for (int ct=0;ct<2;ct++)
        acc[rt][ct] = __builtin_amdgcn_mfma_f32_16x16x32_bf16(af[rt], bf[ct], acc[rt][ct], 0,0,0);
  };

  // prologue
  stage(0, 0);
  asm volatile("s_waitcnt vmcnt(0)" ::: "memory");
  __builtin_amdgcn_s_barrier();

  int cur = 0;
  for (int kt = 0; kt < nkt-1; kt++){
    stage(kt+1, 4096 - cur);          // issue next-step loads (other buffer)
    compute(cur);                      // MFMA on current (hides load latency)
    asm volatile("s_waitcnt vmcnt(0)" ::: "memory");
    __builtin_amdgcn_s_barrier();      // next buffer ready; cur free to restage
    cur = 4096 - cur;
  }
  compute(cur);                        // final K-step, no prefetch

  if (EPI == 0){
    const int y = blockIdx.y;
    if (y == 0){
      #pragma unroll
      for (int rt=0;rt<4;rt++)
        #pragma unroll
        for (int rr=0;rr<4;rr++){
          const int row_g = r0 + rh*64 + rt*16 + quad*4 + rr;
          #pragma unroll
          for (int ct=0;ct<2;ct++){
            const int c = ch*32 + ct*16 + l15;
            float v = (acc[rt][ct][rr] + bias[c]) * scaleq;
            OutB[(long)row_g*128 + c] = f2b(v);
          }
        }
    } else if (y == 1){
      u16* Kreg = OutB + (size_t)NTOK*128;
      #pragma unroll
      for (int rt=0;rt<4;rt++)
        #pragma unroll
        for (int rr=0;rr<4;rr++){
          const int row_g = r0 + rh*64 + rt*16 + quad*4 + rr;
          const int wi = row_g / 392, key = row_g - wi*392;
          #pragma unroll
          for (int ct=0;ct<2;ct++){
            const int c = ch*32 + ct*16 + l15;
            const int hd = c >> 5, d = c & 31;
            float v = acc[rt][ct][rr] + bias[128 + c];
            Kreg[(size_t)(wi*4 + hd)*KTILE + KADDR(key, d>>3) + (d&7)] = f2b(v);
          }
        }
    } else {
      u16* Vreg = OutB + (size_t)NTOK*256;
      #pragma unroll
      for (int rt=0;rt<4;rt++){
        const int rbase = r0 + rh*64 + rt*16 + quad*4;    // 4-aligned; 392%4==0
        const int wi = rbase / 392, key0 = rbase - wi*392; // -> never crosses w
        #pragma unroll
        for (int ct=0;ct<2;ct++){
          const int c = ch*32 + ct*16 + l15;
          const int hd = c >> 5, d = c & 31;
          const float bb = bias[256 + c];
          u32 lo = cvtpk(acc[rt][ct][0] + bb, acc[rt][ct][1] + bb);
          u32 hi = cvtpk(acc[rt][ct][2] + bb, acc[rt][ct][3] + bb);
          u64 pk = (u64)lo | ((u64)hi << 32);
          *reinterpret_cast<u64*>(&Vreg[(size_t)(wi*4 + hd)*KTILE + (size_t)d*392 + key0]) = pk;
        }
      }
    }
  } else if (LNF == 0){
    #pragma unroll
    for (int rt=0;rt<4;rt++){
      #pragma unroll
      for (int rr=0;rr<4;rr++){
        const int row_g = r0 + rh*64 + rt*16 + quad*4 + rr;
        long pos = 0;
        if (EPI == 2) pos = (long)row_to_pos(row_g, shifted) * CC;
        #pragma unroll
        for (int ct=0;ct<2;ct++){
          const int col_g = n0 + ch*32 + ct*16 + l15;
          float v = acc[rt][ct][rr];
          if (EPI == 1){
            v += bias[col_g];
            v = 0.5f*v*(1.f + erff(v*0.70710678118654752f));
            OutB[(long)row_g*ldo + col_g] = f2b(v);
          } else if (EPI == 2){
            OutF[pos + col_g] = Res[pos + col_g] + v + bias[col_g];
          } else {
            float o = OutF[(long)row_g*CC + col_g] + v;
            if (use_bias) o += bias[col_g];
            OutF[(long)row_g*CC + col_g] = o;
          }
        }
      }
    }
  } else {
    // fused LayerNorm epilogue (requires full 128-col rows: gridDim.y == 1).
    // red scratch lives in As buffer 0; final compute used buffer 1 (nkt even)
    // -> disjoint regions, no barrier needed before the scratch writes.
    float* red = (float*)As;     // [128 rows][4 ch][2 stats] = 4KB
    int pose[4][4];
    #pragma unroll
    for (int rt=0;rt<4;rt++){
      #pragma unroll
      for (int rr=0;rr<4;rr++){
        const int row_g = r0 + rh*64 + rt*16 + quad*4 + rr;
        int pos = (EPI == 2) ? row_to_pos(row_g, shifted) : row_g;
        pose[rt][rr] = pos;
        long pb = (long)pos * CC;
        float s = 0.f, ss = 0.f;
        #pragma unroll
        for (int ct=0;ct<2;ct++){
          const int col_g = n0 + ch*32 + ct*16 + l15;
          float v = acc[rt][ct][rr];
          float o;
          if (EPI == 2) o = Res[pb + col_g] + v + bias[col_g];
          else { o = OutF[pb + col_g] + v; if (use_bias) o += bias[col_g]; }
          OutF[pb + col_g] = o;
          acc[rt][ct][rr] = o;
          s += o; ss += o*o;
        }
        #pragma unroll
        for (int off=1; off<16; off<<=1){
          s  += __shfl_xor(s,  off);
          ss += __shfl_xor(ss, off);
        }
        if (l15 == 0){
          int rl = rh*64 + rt*16 + quad*4 + rr;
          red[rl*8 + ch*2]     = s;
          red[rl*8 + ch*2 + 1] = ss;
        }
      }
    }
    __syncthreads();
    #pragma unroll
    for (int rt=0;rt<4;rt++){
      #pragma unroll
      for (int rr=0;rr<4;rr++){
        const int rl = rh*64 + rt*16 + quad*4 + rr;
        float st = 0.f, sst = 0.f;
        #pragma unroll
        for (int j=0;j<4;j++){
          st  += red[rl*8 + j*2];
          sst += red[rl*8 + j*2 + 1];
        }
        float mean = st*(1.f/128.f);
        float var  = sst*(1.f/128.f) - mean*mean;
        float rstd = rsqrtf(var + 1e-5f);
        long oidx;
        if (LNF == 1) oidx = (long)pose[rt][rr] * CC;            // linear-pos out
        else          oidx = (long)pos_to_row_sh(pose[rt][rr]) * CC; // window out
        #pragma unroll
        for (int ct=0;ct<2;ct++){
          const int col_g = n0 + ch*32 + ct*16 + l15;
          float val = (acc[rt][ct][rr] - mean)*rstd*lng[col_g] + lnb[col_g];
          OutB[oidx + col_g] = f2b(val);
        }
      }
    }
  }
}

// MFMA flash attention, S^T orientation. One block per (window, head); 8 waves
// x 16-row q-tiles (qt += 8). K/V^T staged via linear global_load_lds from the
// packed tiles the qkv GEMM emitted. exp2-DIRECT softmax: no max tracking
// (logits structurally bounded; mask bias -144 -> exp2 -> exact 0). Per-lane
// partial denominator, reduced once per q-tile.
__global__ __launch_bounds__(512, 4) void attn_kernel(
    const u16* __restrict__ qkv, const u32* __restrict__ bm,
    u16* __restrict__ out, int shifted)
{
  __shared__ __align__(16) u16 lds[LDS_U16];

  const int w = blockIdx.x >> 2, head = blockIdx.x & 3;
  const int tid = threadIdx.x, lane = tid & 63, wave = tid >> 6;
  const int quad = lane >> 4, l15 = lane & 15;
  const int wd = w>>6, wh = (w>>3)&7, ww = w&7;
  const int cls = shifted ? (((wd!=0)?4:0) | ((wh==7)?2:0) | ((ww==7)?1:0)) : 0;
  const u32* __restrict__ bmh = bm + (size_t)(cls*NHEAD + head)*BM_PER_HEAD;
  const int pbase = POFF + wave*1024;
  const int swz = l15 & 7;
  const int prow = pbase + l15*64;
  const int q2 = quad >> 1, qh = (quad & 1) << 2;

  // stage K tile (25088B) and V^T tile (25088B), both linear
  {
    const u16* Kg = qkv + (size_t)NTOK*128 + (size_t)(w*4+head)*KTILE;
    const u16* Vg = qkv + (size_t)NTOK*256 + (size_t)(w*4+head)*KTILE;
    #pragma unroll
    for (int n = 0; n < 3; n++){
      GLDS(Kg + n*4096 + wave*512 + (lane<<3), &lds[KOFF + n*4096 + wave*512]);
      GLDS(Vg + n*4096 + wave*512 + (lane<<3), &lds[VOFF + n*4096 + wave*512]);
    }
    if (tid < 32){
      GLDS(Kg + 12288 + (lane<<3), &lds[KOFF + 12288]);
      GLDS(Vg + 12288 + (lane<<3), &lds[VOFF + 12288]);
    }
  }
  __syncthreads();

  for (int qt = wave; qt < 25; qt += 8){
    int iq = qt*16 + l15; if (iq > LL-1) iq = LL-1;
    short8 qf = *reinterpret_cast<const short8*>(
        &qkv[((size_t)(w*LL + iq))*128 + head*HDIM + quad*8]);

    float ls = 0.f;
    f32x4 oc0 = {0.f,0.f,0.f,0.f}, oc1 = {0.f,0.f,0.f,0.f};

    const int bmrow = iq*16 + quad*4;
    u32x4 bmA = *reinterpret_cast<const u32x4*>(&bmh[bmrow]);            // s=0
    u32x4 bmB = *reinterpret_cast<const u32x4*>(&bmh[392*16 + bmrow]);   // s=1
    short8 kf0 = *reinterpret_cast<const short8*>(&lds[KOFF + KADDR(     l15, quad)]);
    short8 kf1 = *reinterpret_cast<const short8*>(&lds[KOFF + KADDR(16 + l15, quad)]);
    short8 kf2 = *reinterpret_cast<const short8*>(&lds[KOFF + KADDR(32 + l15, quad)]);
    short8 kf3 = *reinterpret_cast<const short8*>(&lds[KOFF + KADDR(48 + l15, quad)]);

    for (int it = 0; it < 6; it++){
      const int kb = it*64;
      // prefetch next 64-key group (or the clamped 32-key tail when it==5)
      u32x4 bmAn = {}, bmBn = {};
      short8 kn0 = {}, kn1 = {}, kn2 = {}, kn3 = {};
      if (it < 5){
        bmAn = *reinterpret_cast<const u32x4*>(&bmh[(2*it+2)*392*16 + bmrow]);
        bmBn = *reinterpret_cast<const u32x4*>(&bmh[(2*it+3)*392*16 + bmrow]);
        kn0 = *reinterpret_cast<const short8*>(&lds[KOFF + KADDR(kb + 64 + l15, quad)]);
        kn1 = *reinterpret_cast<const short8*>(&lds[KOFF + KADDR(kb + 80 + l15, quad)]);
        kn2 = *reinterpret_cast<const short8*>(&lds[KOFF + KADDR(kb + 96 + l15, quad)]);
        kn3 = *reinterpret_cast<const short8*>(&lds[KOFF + KADDR(kb +112 + l15, quad)]);
      } else {
        bmAn = *reinterpret_cast<const u32x4*>(&bmh[12*392*16 + bmrow]);
        // tail K rows clamped to real rows 384..391; bias -1e30 kills keys>=392
        kn0 = *reinterpret_cast<const short8*>(&lds[KOFF + KADDR(384 + (l15 & 7), quad)]);
        kn1 = kn0;
      }

      f32x4 z = {0.f,0.f,0.f,0.f};
      __builtin_amdgcn_s_setprio(1);
      f32x4 c0 = __builtin_amdgcn_mfma_f32_16x16x32_bf16(kf0, qf, z, 0,0,0);
      f32x4 c1 = __builtin_amdgcn_mfma_f32_16x16x32_bf16(kf1, qf, z, 0,0,0);
      f32x4 c2 = __builtin_amdgcn_mfma_f32_16x16x32_bf16(kf2, qf, z, 0,0,0);
      f32x4 c3 = __builtin_amdgcn_mfma_f32_16x16x32_bf16(kf3, qf, z, 0,0,0);
      __builtin_amdgcn_s_setprio(0);
      // c0[r]: S[key=kb+quad*4+r][q=iq]; c1: +16; c2: +32; c3: +48 (log2 dom.)

      float p0[4], p1[4], p2[4], p3[4];
      #pragma unroll
      for (int r=0;r<4;r++){
        p0[r] = exp2f(c0[r] + b2f_lo(bmA[r]));
        p1[r] = exp2f(c1[r] + b2f_hi(bmA[r]));
        p2[r] = exp2f(c2[r] + b2f_lo(bmB[r]));
        p3[r] = exp2f(c3[r] + b2f_hi(bmB[r]));
        ls += (p0[r] + p1[r]) + (p2[r] + p3[r]);
      }

      // P -> wave-private LDS (16 rows x 8 granules, granule ^= l15&7)
      u32x2 w0, w1, w2, w3;
      w0.x = cvtpk(p0[0], p0[1]); w0.y = cvtpk(p0[2], p0[3]);
      w1.x = cvtpk(p1[0], p1[1]); w1.y = cvtpk(p1[2], p1[3]);
      w2.x = cvtpk(p2[0], p2[1]); w2.y = cvtpk(p2[2], p2[3]);
      w3.x = cvtpk(p3[0], p3[1]); w3.y = cvtpk(p3[2], p3[3]);
      *reinterpret_cast<u32x2*>(&lds[prow + (((0 + q2) ^ swz) << 3) + qh]) = w0;
      *reinterpret_cast<u32x2*>(&lds[prow + (((2 + q2) ^ swz) << 3) + qh]) = w1;
      *reinterpret_cast<u32x2*>(&lds[prow + (((4 + q2) ^ swz) << 3) + qh]) = w2;
      *reinterpret_cast<u32x2*>(&lds[prow + (((6 + q2) ^ swz) << 3) + qh]) = w3;

      short8 pa0 = *reinterpret_cast<const short8*>(&lds[prow + (((quad    ) ^ swz) << 3)]);
      short8 pa1 = *reinterpret_cast<const short8*>(&lds[prow + (((quad + 4) ^ swz) << 3)]);
      short8 vb00 = *reinterpret_cast<const short8*>(&lds[VADDR(     l15, kb      + quad*8)]);
      short8 vb01 = *reinterpret_cast<const short8*>(&lds[VADDR(16 + l15, kb      + quad*8)]);
      short8 vb10 = *reinterpret_cast<const short8*>(&lds[VADDR(     l15, kb + 32 + quad*8)]);
      short8 vb11 = *reinterpret_cast<const short8*>(&lds[VADDR(16 + l15, kb + 32 + quad*8)]);
      __builtin_amdgcn_s_setprio(1);
      oc0 = __builtin_amdgcn_mfma_f32_16x16x32_bf16(pa0, vb00, oc0, 0,0,0);
      oc1 = __builtin_amdgcn_mfma_f32_16x16x32_bf16(pa0, vb01, oc1, 0,0,0);
      oc0 = __builtin_amdgcn_mfma_f32_16x16x32_bf16(pa1, vb10, oc0, 0,0,0);
      oc1 = __builtin_amdgcn_mfma_f32_16x16x32_bf16(pa1, vb11, oc1, 0,0,0);
      __builtin_amdgcn_s_setprio(0);

      bmA = bmAn; bmB = bmBn;
      kf0 = kn0; kf1 = kn1; kf2 = kn2; kf3 = kn3;
    }

    // tail: keys 384..415 (K rows clamped; bias kills keys >= 392)
    {
      f32x4 z = {0.f,0.f,0.f,0.f};
      f32x4 c0 = __builtin_amdgcn_mfma_f32_16x16x32_bf16(kf0, qf, z, 0,0,0);
      f32x4 c1 = __builtin_amdgcn_mfma_f32_16x16x32_bf16(kf1, qf, z, 0,0,0);
      float p0[4], p1[4];
      #pragma unroll
      for (int r=0;r<4;r++){
        p0[r] = exp2f(c0[r] + b2f_lo(bmA[r]));
        p1[r] = exp2f(c1[r] + b2f_hi(bmA[r]));
        ls += p0[r] + p1[r];
      }
      u32x2 w0, w1;
      w0.x = cvtpk(p0[0], p0[1]); w0.y = cvtpk(p0[2], p0[3]);
      w1.x = cvtpk(p1[0], p1[1]); w1.y = cvtpk(p1[2], p1[3]);
      *reinterpret_cast<u32x2*>(&lds[prow + (((0 + q2) ^ swz) << 3) + qh]) = w0;
      *reinterpret_cast<u32x2*>(&lds[prow + (((2 + q2) ^ swz) << 3) + qh]) = w1;
      short8 pa0 = *reinterpret_cast<const short8*>(&lds[prow + ((quad ^ swz) << 3)]);
      // V clamped to keys 384..391 for all k-slots; P==0 for keys >= 392
      short8 vb0 = *reinterpret_cast<const short8*>(&lds[VADDR(     l15, 384)]);
      short8 vb1 = *reinterpret_cast<const short8*>(&lds[VADDR(16 + l15, 384)]);
      oc0 = __builtin_amdgcn_mfma_f32_16x16x32_bf16(pa0, vb0, oc0, 0,0,0);
      oc1 = __builtin_amdgcn_mfma_f32_16x16x32_bf16(pa0, vb1, oc1, 0,0,0);
    }

    // denominator: reduce per-lane partials once per q-tile
    ls += __shfl_xor(ls, 16);
    ls += __shfl_xor(ls, 32);
    float inv = 1.f / ls;
    #pragma unroll
    for (int r=0;r<4;r++){
      float invr = __shfl(inv, quad*4 + r);
      int i = qt*16 + quad*4 + r;
      if (i < LL){
        long o = ((long)(w*LL + i))*CC + head*HDIM;
        out[o + l15]      = f2b(oc0[r]*invr);
        out[o + 16 + l15] = f2b(oc1[r]*invr);
      }
    }
  }
}

extern "C" void kernel_launch(void* const* d_in, const int* in_sizes, int n_in,
                              void* d_out, int out_size, void* d_ws, size_t ws_size,
                              hipStream_t stream)
{
  const float* x     = (const float*)d_in[0];
  const float* ln1g  = (const float*)d_in[1];
  const float* ln1b  = (const float*)d_in[2];
  const float* qkvw  = (const float*)d_in[3];
  const float* qkvb  = (const float*)d_in[4];
  const float* rpb   = (const float*)d_in[5];
  const float* projw = (const float*)d_in[6];
  const float* projb = (const float*)d_in[7];
  const float* ln2g  = (const float*)d_in[8];
  const float* ln2b  = (const float*)d_in[9];
  const float* fc1w  = (const float*)d_in[10];
  const float* fc1b  = (const float*)d_in[11];
  const float* fc2w  = (const float*)d_in[12];
  const float* fc2b  = (const float*)d_in[13];
  float* outf = (float*)d_out;                  // f32 residual stream / output

  u16* buf1 = (u16*)d_ws;                       // bf16 act (window space), NTOK*128
  u16* bufq = buf1 + (size_t)NTOK*CC;           // Q | Kpack | V^T  (NTOK*384 u16)
  u16* ln2o = bufq + (size_t)NTOK*256;          // LN2 out (overlays V^T, dead then)
  u16* hid  = bufq + (size_t)NTOK*384;          // MLP hidden, NTOK*512 u16
  u16* wts  = hid  + (size_t)NTOK*512;          // transposed bf16 weights
  u32* bm   = (u32*)(wts + 393216);             // packed bias+mask table

  // all weight transposes in one launch
  wtall_kernel<<<1536, 256, 0, stream>>>(qkvw, projw, fc1w, fc2w, wts);

  for (int blk = 0; blk < 2; ++blk){
    const int sh = blk;
    const float* resid = (blk==0) ? x : outf;
    u16* wb = wts + (size_t)blk*196608;

    // block 0 (unshifted) only uses mask class 0 -> build 1/8 of the table
    const int bmtot = (blk==0) ? 4*BM_PER_HEAD : BM_TOTAL;
    biasm_kernel<<<(bmtot+255)/256, 256, 0, stream>>>(
        rpb + (size_t)blk*2535*NHEAD, bm, bmtot);
    // LN1 + roll + window gather: separate kernel only for block 0 (from x);
    // block 1's LN1 is fused into block 0's fc2 epilogue.
    if (blk == 0)
      ln_kernel<<<NTOK/4, 256, 0, stream>>>(resid,
          ln1g, ln1b, buf1, 1, 0);
    // QKV GEMM -> packed attention tiles (q pre-scaled by 32^-0.5 * log2e)
    mm_kernel<128,0,0><<<dim3(392,3), 512, 0, stream>>>(
        buf1, wb, 128, qkvb + blk*384, bufq, 128,
        nullptr, nullptr, nullptr, nullptr, QKSCALE*LOG2E, 0, 0);
    // attention (128 windows x 4 heads), 8 waves/block
    attn_kernel<<<NWIN*NHEAD, 512, 0, stream>>>(bufq, bm, buf1, sh);
    // proj + reverse/roll-back scatter + residual -> outf; fused LN2 -> ln2o
    mm_kernel<128,2,1><<<dim3(392,1), 512, 0, stream>>>(
        buf1, wb+49152, 128, projb + blk*CC, ln2o, 0,
        outf, resid, ln2g + blk*CC, ln2b + blk*CC, 1.f, sh, 0);
    // MLP: fc1 one launch (4 column-blocks) -> hid[NTOK][512]
    mm_kernel<128,1,0><<<dim3(392,4), 512, 0, stream>>>(
        ln2o, wb + 65536, 128,
        fc1b + blk*512, hid, 512,
        nullptr, nullptr, nullptr, nullptr, 1.f, 0, 0);
    // fc2 one launch, KD=512, +bias, +residual(outf in place)
    if (blk == 0){
      // fuse LN1(+shifted window gather) for block 1 -> buf1
      mm_kernel<512,3,2><<<dim3(392,1), 512, 0, stream>>>(
          hid, wb + 131072, 512,
          fc2b, buf1, 0,
          outf, nullptr, ln1g + CC, ln1b + CC, 1.f, 0, 1);
    } else {
      mm_kernel<512,3,0><<<dim3(392,1), 512, 0, stream>>>(
          hid, wb + 131072, 512,
          fc2b + CC, nullptr, 0,
          outf, nullptr, nullptr, nullptr, 1.f, 0, 1);
    }
  }
}